// Round 1
// baseline (461.225 us; speedup 1.0000x reference)
//
#include <hip/hip_runtime.h>
#include <hip/hip_bf16.h>
#include <cstdint>

// Problem constants (from reference)
#define N_NODES 20000
#define N_EDGES 640000

// ---------------------------------------------------------------------------
// Preprocessing kernels: build CSR by destination + dinv = rsqrt(indeg+1)
// ---------------------------------------------------------------------------

__global__ void count_deg_kernel(const int* __restrict__ dst, int* __restrict__ deg) {
    int e = blockIdx.x * blockDim.x + threadIdx.x;
    if (e < N_EDGES) {
        atomicAdd(&deg[dst[e]], 1);
    }
}

// Single-block exclusive scan over deg[0..N), also writes cursor copy and dinv.
__global__ __launch_bounds__(1024) void scan_deg_kernel(const int* __restrict__ deg,
                                                        int* __restrict__ row_start,
                                                        int* __restrict__ cursor,
                                                        float* __restrict__ dinv) {
    __shared__ int sdata[1024];
    __shared__ int soffset;
    const int t = threadIdx.x;
    if (t == 0) soffset = 0;
    __syncthreads();
    for (int base = 0; base < N_NODES; base += 1024) {
        int i = base + t;
        int v = (i < N_NODES) ? deg[i] : 0;
        if (i < N_NODES) {
            // deg counts incoming edges; +1 for the self-loop. Always > 0.
            dinv[i] = rsqrtf((float)(v + 1));
        }
        sdata[t] = v;
        __syncthreads();
        // Hillis-Steele inclusive scan
        #pragma unroll
        for (int off = 1; off < 1024; off <<= 1) {
            int x = (t >= off) ? sdata[t - off] : 0;
            __syncthreads();
            sdata[t] += x;
            __syncthreads();
        }
        int incl  = sdata[t];
        int total = sdata[1023];           // read before the update barrier
        int excl  = incl - v + soffset;
        if (i < N_NODES) {
            row_start[i] = excl;
            cursor[i]    = excl;
        }
        __syncthreads();                   // everyone done reading soffset/sdata
        if (t == 0) soffset += total;
        __syncthreads();                   // update visible before next chunk
    }
    if (t == 0) row_start[N_NODES] = soffset;   // == N_EDGES
}

__global__ void fill_col_kernel(const int* __restrict__ src, const int* __restrict__ dst,
                                int* __restrict__ cursor, int* __restrict__ col) {
    int e = blockIdx.x * blockDim.x + threadIdx.x;
    if (e < N_EDGES) {
        int d = dst[e];
        int pos = atomicAdd(&cursor[d], 1);
        col[pos] = src[e];
    }
}

// ---------------------------------------------------------------------------
// Aggregation: out[n][m] = dinv[n] * ( sum_{s in N_in(n)} dinv[s]*x[s][m]
//                                      + dinv[n]*x[n][m] )  (+ bias[m])
// One block per node, one thread per channel. Edge srcs staged through LDS.
// ---------------------------------------------------------------------------

template<int M, bool BIAS>
__global__ void agg_kernel(const float* __restrict__ x,
                           const int* __restrict__ row_start,
                           const int* __restrict__ col,
                           const float* __restrict__ dinv,
                           const float* __restrict__ bias,
                           float* __restrict__ out) {
    constexpr int CHUNK = 64;
    __shared__ int   scol[CHUNK];
    __shared__ float sw[CHUNK];
    const int n = blockIdx.x;
    const int m = threadIdx.x;            // 0..M-1  (M is 128 or 256)
    const float dn = dinv[n];
    const int s0 = row_start[n];
    const int s1 = row_start[n + 1];
    float acc0 = dn * x[(size_t)n * M + m];   // self-loop term
    float acc1 = 0.0f;
    for (int base = s0; base < s1; base += CHUNK) {
        const int cnt = min(CHUNK, s1 - base);
        if (m < cnt) {
            int s = col[base + m];
            scol[m] = s;
            sw[m]   = dinv[s];
        }
        __syncthreads();
        int k = 0;
        for (; k + 1 < cnt; k += 2) {
            acc0 += sw[k]     * x[(size_t)scol[k]     * M + m];
            acc1 += sw[k + 1] * x[(size_t)scol[k + 1] * M + m];
        }
        if (k < cnt) acc0 += sw[k] * x[(size_t)scol[k] * M + m];
        __syncthreads();
    }
    float r = dn * (acc0 + acc1);
    if (BIAS) r += bias[m];
    out[(size_t)n * M + m] = r;
}

// ---------------------------------------------------------------------------
// FP32 GEMM: C[N x M] = A[N x K] @ B[K x M] (+ bias, + ReLU)
// BM=64, BN=64, BK=16, 256 threads, 4x4 microtile per thread.
// ---------------------------------------------------------------------------

template<int K, int M, bool RELUBIAS>
__global__ __launch_bounds__(256) void gemm_kernel(const float* __restrict__ A,
                                                   const float* __restrict__ B,
                                                   const float* __restrict__ bias,
                                                   float* __restrict__ C) {
    __shared__ __align__(16) float As[16][68];   // [k][m], padded row (272B, 16B-aligned)
    __shared__ __align__(16) float Bs[16][64];   // [k][n]

    const int t  = threadIdx.x;
    const int tx = t & 15;        // col group 0..15
    const int ty = t >> 4;        // row group 0..15
    const int bm = blockIdx.x * 64;
    const int bn = blockIdx.y * 64;

    // A tile load mapping: each thread loads one float4
    const int ar = t >> 2;          // 0..63 (row within tile)
    const int ak = (t & 3) * 4;     // 0,4,8,12 (k within tile)
    // B tile load mapping
    const int brow = t >> 4;        // 0..15
    const int bcol = (t & 15) * 4;  // 0..60

    float acc[4][4] = {};

    for (int k0 = 0; k0 < K; k0 += 16) {
        float4 av = make_float4(0.f, 0.f, 0.f, 0.f);
        const int grow = bm + ar;
        if (grow < N_NODES)
            av = *reinterpret_cast<const float4*>(A + (size_t)grow * K + k0 + ak);
        As[ak + 0][ar] = av.x;
        As[ak + 1][ar] = av.y;
        As[ak + 2][ar] = av.z;
        As[ak + 3][ar] = av.w;

        float4 bv = *reinterpret_cast<const float4*>(B + (size_t)(k0 + brow) * M + bn + bcol);
        *reinterpret_cast<float4*>(&Bs[brow][bcol]) = bv;

        __syncthreads();

        #pragma unroll
        for (int kk = 0; kk < 16; ++kk) {
            float4 aq = *reinterpret_cast<const float4*>(&As[kk][ty * 4]);
            float4 bq = *reinterpret_cast<const float4*>(&Bs[kk][tx * 4]);
            float a[4] = {aq.x, aq.y, aq.z, aq.w};
            float b[4] = {bq.x, bq.y, bq.z, bq.w};
            #pragma unroll
            for (int i = 0; i < 4; ++i)
                #pragma unroll
                for (int j = 0; j < 4; ++j)
                    acc[i][j] += a[i] * b[j];
        }
        __syncthreads();
    }

    // Epilogue
    float bvals[4] = {0.f, 0.f, 0.f, 0.f};
    if (RELUBIAS) {
        #pragma unroll
        for (int j = 0; j < 4; ++j) bvals[j] = bias[bn + tx * 4 + j];
    }
    #pragma unroll
    for (int i = 0; i < 4; ++i) {
        const int row = bm + ty * 4 + i;
        if (row < N_NODES) {
            float4 r;
            float v0 = acc[i][0], v1 = acc[i][1], v2 = acc[i][2], v3 = acc[i][3];
            if (RELUBIAS) {
                v0 = fmaxf(v0 + bvals[0], 0.f);
                v1 = fmaxf(v1 + bvals[1], 0.f);
                v2 = fmaxf(v2 + bvals[2], 0.f);
                v3 = fmaxf(v3 + bvals[3], 0.f);
            }
            r.x = v0; r.y = v1; r.z = v2; r.w = v3;
            *reinterpret_cast<float4*>(C + (size_t)row * M + bn + tx * 4) = r;
        }
    }
}

// ---------------------------------------------------------------------------
// Launch
// ---------------------------------------------------------------------------

static inline char* align_up(char* p, size_t a) {
    return (char*)(((uintptr_t)p + a - 1) & ~(a - 1));
}

extern "C" void kernel_launch(void* const* d_in, const int* in_sizes, int n_in,
                              void* d_out, int out_size, void* d_ws, size_t ws_size,
                              hipStream_t stream) {
    const int*   edge_index = (const int*)d_in[0];      // [2, E]
    const float* node_emb   = (const float*)d_in[1];    // [N, 128]
    const float* W1 = (const float*)d_in[2];            // [128, 256]
    const float* b1 = (const float*)d_in[3];
    const float* W2 = (const float*)d_in[4];            // [256, 256]
    const float* b2 = (const float*)d_in[5];
    const float* W3 = (const float*)d_in[6];            // [256, 128]
    const float* b3 = (const float*)d_in[7];
    float* out = (float*)d_out;                          // [N, 128]

    const int* src = edge_index;             // row 0
    const int* dst = edge_index + N_EDGES;   // row 1

    // Workspace carve-up (~43.8 MB total)
    char* p = (char*)d_ws;
    int* deg       = (int*)p;                 p = align_up(p + N_NODES * sizeof(int), 256);
    int* row_start = (int*)p;                 p = align_up(p + (N_NODES + 1) * sizeof(int), 256);
    int* cursor    = (int*)p;                 p = align_up(p + N_NODES * sizeof(int), 256);
    int* col       = (int*)p;                 p = align_up(p + N_EDGES * sizeof(int), 256);
    float* dinv    = (float*)p;               p = align_up(p + N_NODES * sizeof(float), 256);
    float* bufA    = (float*)p;               p = align_up(p + (size_t)N_NODES * 256 * sizeof(float), 256);
    float* bufB    = (float*)p;               p = align_up(p + (size_t)N_NODES * 256 * sizeof(float), 256);

    // --- Build CSR (graph identical across all 3 layers) ---
    hipMemsetAsync(deg, 0, N_NODES * sizeof(int), stream);
    count_deg_kernel<<<(N_EDGES + 255) / 256, 256, 0, stream>>>(dst, deg);
    scan_deg_kernel<<<1, 1024, 0, stream>>>(deg, row_start, cursor, dinv);
    fill_col_kernel<<<(N_EDGES + 255) / 256, 256, 0, stream>>>(src, dst, cursor, col);

    const dim3 gemm_block(256);
    const int grid_m = (N_NODES + 63) / 64;   // 313

    // --- Layer 1: t = Agg(node_emb) [N,128]; h1 = relu(t @ W1 + b1) [N,256] ---
    agg_kernel<128, false><<<N_NODES, 128, 0, stream>>>(node_emb, row_start, col, dinv, nullptr, bufA);
    gemm_kernel<128, 256, true><<<dim3(grid_m, 4), gemm_block, 0, stream>>>(bufA, W1, b1, bufB);

    // --- Layer 2: t2 = Agg(h1) [N,256]; h2 = relu(t2 @ W2 + b2) [N,256] ---
    agg_kernel<256, false><<<N_NODES, 256, 0, stream>>>(bufB, row_start, col, dinv, nullptr, bufA);
    gemm_kernel<256, 256, true><<<dim3(grid_m, 4), gemm_block, 0, stream>>>(bufA, W2, b2, bufB);

    // --- Layer 3: h3 = h2 @ W3 [N,128]; out = Agg(h3) + b3 ---
    gemm_kernel<256, 128, false><<<dim3(grid_m, 2), gemm_block, 0, stream>>>(bufB, W3, nullptr, bufA);
    agg_kernel<128, true><<<N_NODES, 128, 0, stream>>>(bufA, row_start, col, dinv, b3, out);
}